// Round 6
// baseline (34.954 us; speedup 1.0000x reference)
//
#include <hip/hip_runtime.h>

#define DIM 128
#define LEN 256
#define INV_SQRT_D 0.08838834764831845f
#define LOG2E 1.4426950408889634f
#define SCALE_L2 (INV_SQRT_D * LOG2E)

// ws layout (floats): Mt[128*128], c[128], w2[128], bqbk[1], pad7,
//                     v[B*128] (pre-scaled), q0bk[B] (pre-scaled), bf16 sub_feat (S*D ushorts)
#define WS_MT   0
#define WS_C    (DIM * DIM)
#define WS_W2   (DIM * DIM + DIM)
#define WS_BQBK (DIM * DIM + 2 * DIM)
#define WS_VBUF (DIM * DIM + 2 * DIM + 8)

__device__ __forceinline__ float bl(unsigned u) { return __uint_as_float(u << 16); }
__device__ __forceinline__ float bh(unsigned u) { return __uint_as_float(u & 0xffff0000u); }

// ---- precompute: Mt[j][i] = sum_d Wk[i,d]*Wq[j,d]; c = Wk@bq; w2 = Wq@bk; bqbk ----
__global__ __launch_bounds__(128) void precompute_kernel(
    const float* __restrict__ Wq, const float* __restrict__ bq,
    const float* __restrict__ Wk, const float* __restrict__ bk,
    float* __restrict__ ws)
{
    const int t = threadIdx.x;
    const int j = blockIdx.x;
    if (j < DIM) {
        __shared__ float wqj[DIM];
        wqj[t] = Wq[j * DIM + t];
        __syncthreads();
        const float4* row = reinterpret_cast<const float4*>(Wk + t * DIM);
        float acc = 0.f;
        #pragma unroll 8
        for (int i = 0; i < DIM / 4; ++i) {
            float4 u = row[i];
            acc = fmaf(u.x, wqj[4*i+0], acc);
            acc = fmaf(u.y, wqj[4*i+1], acc);
            acc = fmaf(u.z, wqj[4*i+2], acc);
            acc = fmaf(u.w, wqj[4*i+3], acc);
        }
        ws[WS_MT + j * DIM + t] = acc;
    } else {
        __shared__ float bqs[DIM], bks[DIM], red[DIM];
        bqs[t] = bq[t]; bks[t] = bk[t];
        __syncthreads();
        const float4* rk = reinterpret_cast<const float4*>(Wk + t * DIM);
        const float4* rq = reinterpret_cast<const float4*>(Wq + t * DIM);
        float accC = 0.f, accW = 0.f;
        #pragma unroll 8
        for (int i = 0; i < DIM / 4; ++i) {
            float4 a  = rk[i];
            float4 b2 = rq[i];
            accC = fmaf(a.x,  bqs[4*i+0], accC);
            accC = fmaf(a.y,  bqs[4*i+1], accC);
            accC = fmaf(a.z,  bqs[4*i+2], accC);
            accC = fmaf(a.w,  bqs[4*i+3], accC);
            accW = fmaf(b2.x, bks[4*i+0], accW);
            accW = fmaf(b2.y, bks[4*i+1], accW);
            accW = fmaf(b2.z, bks[4*i+2], accW);
            accW = fmaf(b2.w, bks[4*i+3], accW);
        }
        ws[WS_C  + t] = accC;
        ws[WS_W2 + t] = accW;
        red[t] = bqs[t] * bks[t];
        __syncthreads();
        if (t == 0) {
            float s = 0.f;
            for (int i = 0; i < DIM; ++i) s += red[i];
            ws[WS_BQBK] = s;
        }
    }
}

// ---- convert sub_feat f32 -> bf16 (RNE) into ws ----
__global__ __launch_bounds__(256) void convert_kernel(
    const float* __restrict__ src, ushort* __restrict__ dst, int n4)
{
    const int i = blockIdx.x * 256 + threadIdx.x;
    if (i < n4) {
        const float4 u = reinterpret_cast<const float4*>(src)[i];
        ushort4 o;
        unsigned a;
        a = __float_as_uint(u.x); o.x = (ushort)((a + 0x7fffu + ((a >> 16) & 1u)) >> 16);
        a = __float_as_uint(u.y); o.y = (ushort)((a + 0x7fffu + ((a >> 16) & 1u)) >> 16);
        a = __float_as_uint(u.z); o.z = (ushort)((a + 0x7fffu + ((a >> 16) & 1u)) >> 16);
        a = __float_as_uint(u.w); o.w = (ushort)((a + 0x7fffu + ((a >> 16) & 1u)) >> 16);
        reinterpret_cast<ushort4*>(dst)[i] = o;
    }
}

// ---- vcompute: v[b] = (Mt·g0_b + c)·SCALE_L2 (Mt in LDS), q0bk[b]·SCALE_L2 ----
__global__ __launch_bounds__(256) void vcompute_kernel(
    const float* __restrict__ sub_feat, const int* __restrict__ sub_index,
    const float* __restrict__ ws, float* __restrict__ vout,
    float* __restrict__ qout, int B)
{
    const int t    = threadIdx.x;
    const int lane = t & 63;
    const int wv   = t >> 6;

    __shared__ float MtL[DIM * DIM];
    __shared__ float g0L[4][DIM];

    const float4* Msrc = reinterpret_cast<const float4*>(ws + WS_MT);
    float4* Mdst = reinterpret_cast<float4*>(MtL);
    #pragma unroll
    for (int i = 0; i < 16; ++i) Mdst[t + 256 * i] = Msrc[t + 256 * i];
    __syncthreads();

    const float* w2 = ws + WS_W2;
    const float* cc = ws + WS_C;
    const float  bqbk = ws[WS_BQBK];

    #pragma unroll
    for (int s = 0; s < 2; ++s) {
        const int b = blockIdx.x * 8 + wv * 2 + s;
        if (b >= B) break;
        const int r0 = sub_index[(size_t)b * LEN];
        const float2 g0p = reinterpret_cast<const float2*>(sub_feat + (size_t)r0 * DIM)[lane];
        g0L[wv][2 * lane]     = g0p.x;
        g0L[wv][2 * lane + 1] = g0p.y;

        float qp = g0p.x * w2[2 * lane] + g0p.y * w2[2 * lane + 1];
        #pragma unroll
        for (int o = 32; o > 0; o >>= 1) qp += __shfl_xor(qp, o);
        if (lane == 0) qout[b] = (qp + bqbk) * SCALE_L2;

        float a0 = 0.f, a1 = 0.f;
        #pragma unroll 8
        for (int j = 0; j < DIM; ++j) {
            const float g = g0L[wv][j];
            a0 = fmaf(g, MtL[j * DIM + lane],      a0);
            a1 = fmaf(g, MtL[j * DIM + lane + 64], a1);
        }
        vout[(size_t)b * DIM + lane]      = (a0 + cc[lane])      * SCALE_L2;
        vout[(size_t)b * DIM + lane + 64] = (a1 + cc[lane + 64]) * SCALE_L2;
    }
}

// ---- main: 1 block = 1 batch, 4 waves x 64 rows, bf16 gathers, no-max exp2 softmax ----
__global__ __launch_bounds__(256, 8) void attn_kernel(
    const ushort* __restrict__ gfeat, const float* __restrict__ mask,
    const int* __restrict__ sub_index, const float* __restrict__ vbuf,
    const float* __restrict__ qbuf, float* __restrict__ out)
{
    const int t    = threadIdx.x;
    const int lane = t & 63;
    const int wv   = t >> 6;
    const int b    = blockIdx.x;
    const int g    = lane >> 4;
    const int m16  = lane & 15;

    __shared__ int   idw[LEN];
    __shared__ float bw [LEN];
    __shared__ float OW [4][DIM];
    __shared__ float Zw [4];

    // stage indices + mask-bias (each wave writes its own 64-segment; wave-ordered)
    idw[t] = sub_index[(size_t)b * LEN + t];
    bw[t]  = (1.f - mask[(size_t)b * LEN + t]) * (-10000.f * LOG2E);

    // per-lane v slice: dims 8*m16 .. 8*m16+7 (pre-scaled by 1/sqrtD*log2e)
    const float4 va = reinterpret_cast<const float4*>(vbuf + (size_t)b * DIM)[2 * m16];
    const float4 vb = reinterpret_cast<const float4*>(vbuf + (size_t)b * DIM)[2 * m16 + 1];
    const float qterm = qbuf[b];

    float Zr = 0.f;
    float O0=0.f,O1=0.f,O2=0.f,O3=0.f,O4=0.f,O5=0.f,O6=0.f,O7=0.f;

    const int jbase = wv * 64;
    #pragma unroll 4
    for (int k = 0; k < 16; ++k) {
        const int jl = jbase + 4 * k + g;
        const int ij = idw[jl];
        const float bj = bw[jl];
        // one dwordx4 per lane = 8 bf16 dims; 16 lanes cover the whole 128-dim row
        const uint4 u = *reinterpret_cast<const uint4*>(gfeat + (size_t)ij * DIM + 8 * m16);
        const float f0 = bl(u.x), f1 = bh(u.x), f2 = bl(u.y), f3 = bh(u.y);
        const float f4 = bl(u.z), f5 = bh(u.z), f6 = bl(u.w), f7 = bh(u.w);
        float sd = f0*va.x + f1*va.y + f2*va.z + f3*va.w
                 + f4*vb.x + f5*vb.y + f6*vb.z + f7*vb.w;
        sd += __shfl_xor(sd, 1);
        sd += __shfl_xor(sd, 2);
        sd += __shfl_xor(sd, 4);
        sd += __shfl_xor(sd, 8);
        const float e = exp2f(sd + qterm + bj);
        Zr += e;
        O0 = fmaf(e, f0, O0); O1 = fmaf(e, f1, O1);
        O2 = fmaf(e, f2, O2); O3 = fmaf(e, f3, O3);
        O4 = fmaf(e, f4, O4); O5 = fmaf(e, f5, O5);
        O6 = fmaf(e, f6, O6); O7 = fmaf(e, f7, O7);
    }

    // merge 4 groups within the wave
    #pragma unroll
    for (int msk = 16; msk <= 32; msk <<= 1) {
        Zr += __shfl_xor(Zr, msk);
        O0 += __shfl_xor(O0, msk); O1 += __shfl_xor(O1, msk);
        O2 += __shfl_xor(O2, msk); O3 += __shfl_xor(O3, msk);
        O4 += __shfl_xor(O4, msk); O5 += __shfl_xor(O5, msk);
        O6 += __shfl_xor(O6, msk); O7 += __shfl_xor(O7, msk);
    }
    if (lane < 16) {
        reinterpret_cast<float4*>(&OW[wv][0])[2 * m16]     = make_float4(O0, O1, O2, O3);
        reinterpret_cast<float4*>(&OW[wv][0])[2 * m16 + 1] = make_float4(O4, O5, O6, O7);
    }
    if (lane == 0) Zw[wv] = Zr;
    __syncthreads();

    if (t < DIM) {
        const float Zt = Zw[0] + Zw[1] + Zw[2] + Zw[3];
        out[(size_t)b * DIM + t] =
            (OW[0][t] + OW[1][t] + OW[2][t] + OW[3][t]) / Zt;
    }
}

// ---- fallback (round-4 fused path, f32 gathers) if ws is too small ----
__global__ __launch_bounds__(256) void fused_fallback(
    const float* __restrict__ sub_feat, const float* __restrict__ mask,
    const int* __restrict__ sub_index, const float* __restrict__ ws,
    float* __restrict__ out)
{
    const int t    = threadIdx.x;
    const int lane = t & 63;
    const int wv   = t >> 6;
    const int pair = wv >> 1;
    const int rhalf= wv & 1;
    const int b    = blockIdx.x * 2 + pair;
    const int c32  = lane & 31;
    const int h    = lane >> 5;
    const int g    = lane >> 4;
    const int m16  = lane & 15;

    const float* Mt = ws + WS_MT;
    const float* cc = ws + WS_C;
    const float* w2 = ws + WS_W2;

    __shared__ float g0s [4][DIM];
    __shared__ int   idxs[4][DIM];
    __shared__ float bias[4][DIM];
    __shared__ float OW  [4][DIM];
    __shared__ float Zw  [4];

    float* g0w = g0s[wv];
    int*   idw = idxs[wv];
    float* bww = bias[wv];

    const int*   ib = sub_index + (size_t)b * LEN + rhalf * DIM;
    const float* mb = mask      + (size_t)b * LEN + rhalf * DIM;
    idw[lane]      = ib[lane];
    idw[lane + 64] = ib[lane + 64];
    bww[lane]      = (1.f - mb[lane])      * (-10000.f * LOG2E);
    bww[lane + 64] = (1.f - mb[lane + 64]) * (-10000.f * LOG2E);

    const int r0 = sub_index[(size_t)b * LEN];
    const float2 g0p = reinterpret_cast<const float2*>(sub_feat + (size_t)r0 * DIM)[lane];
    g0w[2 * lane]     = g0p.x;
    g0w[2 * lane + 1] = g0p.y;

    float qp = g0p.x * w2[2 * lane] + g0p.y * w2[2 * lane + 1];
    #pragma unroll
    for (int o = 32; o > 0; o >>= 1) qp += __shfl_xor(qp, o);
    const float qterm = (qp + ws[WS_BQBK]) * SCALE_L2;

    float4 vacc = make_float4(0.f, 0.f, 0.f, 0.f);
    {
        const int jb = h * 64;
        #pragma unroll 8
        for (int k = 0; k < 64; ++k) {
            const int j = jb + k;
            const float gg = g0w[j];
            const float4 u = reinterpret_cast<const float4*>(Mt + j * DIM)[c32];
            vacc.x = fmaf(gg, u.x, vacc.x);
            vacc.y = fmaf(gg, u.y, vacc.y);
            vacc.z = fmaf(gg, u.z, vacc.z);
            vacc.w = fmaf(gg, u.w, vacc.w);
        }
    }
    vacc.x += __shfl_xor(vacc.x, 32);
    vacc.y += __shfl_xor(vacc.y, 32);
    vacc.z += __shfl_xor(vacc.z, 32);
    vacc.w += __shfl_xor(vacc.w, 32);
    const float4 cv = reinterpret_cast<const float4*>(cc)[c32];
    float4 vt;
    vt.x = (vacc.x + cv.x) * SCALE_L2; vt.y = (vacc.y + cv.y) * SCALE_L2;
    vt.z = (vacc.z + cv.z) * SCALE_L2; vt.w = (vacc.w + cv.w) * SCALE_L2;

    float4 vA, vB;
    vA.x = __shfl(vt.x, m16);      vA.y = __shfl(vt.y, m16);
    vA.z = __shfl(vt.z, m16);      vA.w = __shfl(vt.w, m16);
    vB.x = __shfl(vt.x, m16 + 16); vB.y = __shfl(vt.y, m16 + 16);
    vB.z = __shfl(vt.z, m16 + 16); vB.w = __shfl(vt.w, m16 + 16);

    float Zr = 0.f;
    float O0=0.f,O1=0.f,O2=0.f,O3=0.f,O4=0.f,O5=0.f,O6=0.f,O7=0.f;
    #pragma unroll 4
    for (int k = 0; k < 32; ++k) {
        const int jl = 4 * k + g;
        const int ij = idw[jl];
        const float bj = bww[jl];
        const float* rp = sub_feat + (size_t)ij * DIM + 4 * m16;
        const float4 u0 = *reinterpret_cast<const float4*>(rp);
        const float4 u1 = *reinterpret_cast<const float4*>(rp + 64);
        float sd = u0.x*vA.x + u0.y*vA.y + u0.z*vA.z + u0.w*vA.w
                 + u1.x*vB.x + u1.y*vB.y + u1.z*vB.z + u1.w*vB.w;
        sd += __shfl_xor(sd, 1);
        sd += __shfl_xor(sd, 2);
        sd += __shfl_xor(sd, 4);
        sd += __shfl_xor(sd, 8);
        const float e = exp2f(sd + qterm + bj);
        Zr += e;
        O0 = fmaf(e, u0.x, O0); O1 = fmaf(e, u0.y, O1);
        O2 = fmaf(e, u0.z, O2); O3 = fmaf(e, u0.w, O3);
        O4 = fmaf(e, u1.x, O4); O5 = fmaf(e, u1.y, O5);
        O6 = fmaf(e, u1.z, O6); O7 = fmaf(e, u1.w, O7);
    }
    #pragma unroll
    for (int msk = 16; msk <= 32; msk <<= 1) {
        Zr += __shfl_xor(Zr, msk);
        O0 += __shfl_xor(O0, msk); O1 += __shfl_xor(O1, msk);
        O2 += __shfl_xor(O2, msk); O3 += __shfl_xor(O3, msk);
        O4 += __shfl_xor(O4, msk); O5 += __shfl_xor(O5, msk);
        O6 += __shfl_xor(O6, msk); O7 += __shfl_xor(O7, msk);
    }
    if (lane < 16) {
        reinterpret_cast<float4*>(&OW[wv][0])[m16]  = make_float4(O0, O1, O2, O3);
        reinterpret_cast<float4*>(&OW[wv][64])[m16] = make_float4(O4, O5, O6, O7);
    }
    if (lane == 0) Zw[wv] = Zr;
    __syncthreads();

    {
        const int p = t >> 7;
        const int d = t & (DIM - 1);
        const float Zt = Zw[2*p] + Zw[2*p+1];
        out[((size_t)blockIdx.x * 2 + p) * DIM + d] = (OW[2*p][d] + OW[2*p+1][d]) / Zt;
    }
}

extern "C" void kernel_launch(void* const* d_in, const int* in_sizes, int n_in,
                              void* d_out, int out_size, void* d_ws, size_t ws_size,
                              hipStream_t stream) {
    const float* sub_feat  = (const float*)d_in[0];
    const float* mask      = (const float*)d_in[1];
    const float* Wq        = (const float*)d_in[2];
    const float* bq        = (const float*)d_in[3];
    const float* Wk        = (const float*)d_in[4];
    const float* bk        = (const float*)d_in[5];
    const int*   sub_index = (const int*)d_in[6];
    float* outp = (float*)d_out;
    float* ws   = (float*)d_ws;

    const int B  = in_sizes[6] / LEN;   // 2048
    const int SD = in_sizes[0];         // S*D = 524288

    const size_t WS_BF = (size_t)WS_VBUF + (size_t)B * DIM + (size_t)B;  // float offset
    const size_t needed = (WS_BF + (size_t)(SD + 1) / 2) * sizeof(float);

    precompute_kernel<<<dim3(DIM + 1), dim3(DIM), 0, stream>>>(Wq, bq, Wk, bk, ws);

    if (ws_size >= needed) {
        float*  vbuf = ws + WS_VBUF;
        float*  qbuf = vbuf + (size_t)B * DIM;
        ushort* bfb  = reinterpret_cast<ushort*>(ws + WS_BF);

        convert_kernel<<<dim3((SD / 4 + 255) / 256), dim3(256), 0, stream>>>(
            sub_feat, bfb, SD / 4);
        vcompute_kernel<<<dim3((B + 7) / 8), dim3(256), 0, stream>>>(
            sub_feat, sub_index, ws, vbuf, qbuf, B);
        attn_kernel<<<dim3(B), dim3(256), 0, stream>>>(
            bfb, mask, sub_index, vbuf, qbuf, outp);
    } else {
        fused_fallback<<<dim3(B / 2), dim3(256), 0, stream>>>(
            sub_feat, mask, sub_index, ws, outp);
    }
}

// Round 7
// 29.321 us; speedup vs baseline: 1.1921x; 1.1921x over previous
//
#include <hip/hip_runtime.h>

#define DIM 128
#define LEN 256
#define INV_SQRT_D 0.08838834764831845f
#define LOG2E 1.4426950408889634f
#define SCALE_L2 (INV_SQRT_D * LOG2E)

// ws layout (floats): Mt[128*128] (f32), c[128], w2[128], bqbk[1], pad7, bf16 feat (S*D ushorts)
#define WS_MT   0
#define WS_C    (DIM * DIM)
#define WS_W2   (DIM * DIM + DIM)
#define WS_BQBK (DIM * DIM + 2 * DIM)
#define WS_BF   (DIM * DIM + 2 * DIM + 8)

__device__ __forceinline__ float bl(unsigned u) { return __uint_as_float(u << 16); }
__device__ __forceinline__ float bh(unsigned u) { return __uint_as_float(u & 0xffff0000u); }

// ---- prep: blocks 0..127 -> Mt rows; 128 -> c,w2,bqbk; 129.. -> bf16 convert ----
__global__ __launch_bounds__(256) void prep_kernel(
    const float* __restrict__ sub_feat,
    const float* __restrict__ Wq, const float* __restrict__ bq,
    const float* __restrict__ Wk, const float* __restrict__ bk,
    float* __restrict__ ws, ushort* __restrict__ bfb, int n4)
{
    const int t   = threadIdx.x;
    const int bid = blockIdx.x;

    if (bid < DIM) {
        // Mt[j][i] = sum_d Wk[i,d] * Wq[j,d] ; j = bid, i = t (first 128 threads)
        if (t < DIM) {
            __shared__ float wqj[DIM];
            wqj[t] = Wq[bid * DIM + t];
            __syncthreads();
            const float4* row = reinterpret_cast<const float4*>(Wk + t * DIM);
            float acc = 0.f;
            #pragma unroll 8
            for (int i = 0; i < DIM / 4; ++i) {
                float4 u = row[i];
                acc = fmaf(u.x, wqj[4*i+0], acc);
                acc = fmaf(u.y, wqj[4*i+1], acc);
                acc = fmaf(u.z, wqj[4*i+2], acc);
                acc = fmaf(u.w, wqj[4*i+3], acc);
            }
            ws[WS_MT + bid * DIM + t] = acc;
        } else {
            __syncthreads();
        }
    } else if (bid == DIM) {
        if (t < DIM) {
            __shared__ float bqs[DIM], bks[DIM], red[DIM];
            bqs[t] = bq[t]; bks[t] = bk[t];
            __syncthreads();
            const float4* rk = reinterpret_cast<const float4*>(Wk + t * DIM);
            const float4* rq = reinterpret_cast<const float4*>(Wq + t * DIM);
            float accC = 0.f, accW = 0.f;
            #pragma unroll 8
            for (int i = 0; i < DIM / 4; ++i) {
                float4 a  = rk[i];
                float4 b2 = rq[i];
                accC = fmaf(a.x,  bqs[4*i+0], accC);
                accC = fmaf(a.y,  bqs[4*i+1], accC);
                accC = fmaf(a.z,  bqs[4*i+2], accC);
                accC = fmaf(a.w,  bqs[4*i+3], accC);
                accW = fmaf(b2.x, bks[4*i+0], accW);
                accW = fmaf(b2.y, bks[4*i+1], accW);
                accW = fmaf(b2.z, bks[4*i+2], accW);
                accW = fmaf(b2.w, bks[4*i+3], accW);
            }
            ws[WS_C  + t] = accC;
            ws[WS_W2 + t] = accW;
            red[t] = bqs[t] * bks[t];
            __syncthreads();
            if (t == 0) {
                float s = 0.f;
                for (int i = 0; i < DIM; ++i) s += red[i];
                ws[WS_BQBK] = s;
            }
        } else {
            __syncthreads(); __syncthreads();
        }
    } else {
        // bf16 convert (RNE)
        const int i = (bid - DIM - 1) * 256 + t;
        if (i < n4) {
            const float4 u = reinterpret_cast<const float4*>(sub_feat)[i];
            ushort4 o;
            unsigned a;
            a = __float_as_uint(u.x); o.x = (ushort)((a + 0x7fffu + ((a >> 16) & 1u)) >> 16);
            a = __float_as_uint(u.y); o.y = (ushort)((a + 0x7fffu + ((a >> 16) & 1u)) >> 16);
            a = __float_as_uint(u.z); o.z = (ushort)((a + 0x7fffu + ((a >> 16) & 1u)) >> 16);
            a = __float_as_uint(u.w); o.w = (ushort)((a + 0x7fffu + ((a >> 16) & 1u)) >> 16);
            reinterpret_cast<ushort4*>(bfb)[i] = o;
        }
    }
}

// ---- main: 1 block = 1 batch; cooperative v = Mt*g0 (coalesced), then bf16 score loop ----
__global__ __launch_bounds__(256, 8) void main_kernel(
    const float* __restrict__ sub_feat, const ushort* __restrict__ gfeat,
    const float* __restrict__ mask, const int* __restrict__ sub_index,
    const float* __restrict__ ws, float* __restrict__ out)
{
    const int t    = threadIdx.x;
    const int lane = t & 63;
    const int wv   = t >> 6;
    const int b    = blockIdx.x;
    const int g    = lane >> 4;
    const int m16  = lane & 15;

    __shared__ float2 ibw[LEN];       // .x = idx bits, .y = mask bias (log2 units)
    __shared__ float  g0L[DIM];
    __shared__ float  vh [2][DIM];
    __shared__ float  vL [DIM];
    __shared__ float  OW [4][DIM];
    __shared__ float  Zw [4];
    __shared__ float  qbkL;

    // stage idx + bias packed
    {
        const int   ij = sub_index[(size_t)b * LEN + t];
        const float mk = mask[(size_t)b * LEN + t];
        ibw[t] = make_float2(__int_as_float(ij), (1.f - mk) * (-10000.f * LOG2E));
    }
    // g0 + q0bk by wave 0
    if (t < 64) {
        const int r0 = sub_index[(size_t)b * LEN];
        const float2 g0p = reinterpret_cast<const float2*>(sub_feat + (size_t)r0 * DIM)[t];
        g0L[2 * t]     = g0p.x;
        g0L[2 * t + 1] = g0p.y;
        const float* w2 = ws + WS_W2;
        float qp = g0p.x * w2[2 * t] + g0p.y * w2[2 * t + 1];
        #pragma unroll
        for (int o = 32; o > 0; o >>= 1) qp += __shfl_xor(qp, o);
        if (t == 0) qbkL = (qp + ws[WS_BQBK]) * SCALE_L2;
    }
    __syncthreads();

    // cooperative matvec: vh[h][i] = sum_{j in half h} Mt[j][i] * g0[j]   (coalesced over i)
    {
        const int i  = t & (DIM - 1);
        const int hh = t >> 7;
        const float* Mrow = ws + WS_MT + hh * 64 * DIM;
        const float* gL   = g0L + hh * 64;
        float a = 0.f;
        #pragma unroll 8
        for (int j = 0; j < 64; ++j)
            a = fmaf(gL[j], Mrow[j * DIM + i], a);
        vh[hh][i] = a;
    }
    __syncthreads();
    if (t < DIM) {
        vL[t] = (vh[0][t] + vh[1][t] + ws[WS_C + t]) * SCALE_L2;
    }
    __syncthreads();

    // per-lane v slice: dims 8*m16 .. 8*m16+7 (pre-scaled)
    const float4 va = reinterpret_cast<const float4*>(vL)[2 * m16];
    const float4 vb = reinterpret_cast<const float4*>(vL)[2 * m16 + 1];
    const float qterm = qbkL;

    float Zr = 0.f;
    float O0=0.f,O1=0.f,O2=0.f,O3=0.f,O4=0.f,O5=0.f,O6=0.f,O7=0.f;

    const int jbase = wv * 64;
    #pragma unroll 4
    for (int k = 0; k < 16; ++k) {
        const float2 ibp = ibw[jbase + 4 * k + g];
        const int   ij = __float_as_int(ibp.x);
        const float bj = ibp.y;
        const uint4 u = *reinterpret_cast<const uint4*>(gfeat + (size_t)ij * DIM + 8 * m16);
        const float f0 = bl(u.x), f1 = bh(u.x), f2 = bl(u.y), f3 = bh(u.y);
        const float f4 = bl(u.z), f5 = bh(u.z), f6 = bl(u.w), f7 = bh(u.w);
        float sd = f0*va.x + f1*va.y + f2*va.z + f3*va.w
                 + f4*vb.x + f5*vb.y + f6*vb.z + f7*vb.w;
        sd += __shfl_xor(sd, 1);
        sd += __shfl_xor(sd, 2);
        sd += __shfl_xor(sd, 4);
        sd += __shfl_xor(sd, 8);
        const float e = exp2f(sd + qterm + bj);
        Zr += e;
        O0 = fmaf(e, f0, O0); O1 = fmaf(e, f1, O1);
        O2 = fmaf(e, f2, O2); O3 = fmaf(e, f3, O3);
        O4 = fmaf(e, f4, O4); O5 = fmaf(e, f5, O5);
        O6 = fmaf(e, f6, O6); O7 = fmaf(e, f7, O7);
    }

    // merge 4 groups within the wave
    #pragma unroll
    for (int msk = 16; msk <= 32; msk <<= 1) {
        Zr += __shfl_xor(Zr, msk);
        O0 += __shfl_xor(O0, msk); O1 += __shfl_xor(O1, msk);
        O2 += __shfl_xor(O2, msk); O3 += __shfl_xor(O3, msk);
        O4 += __shfl_xor(O4, msk); O5 += __shfl_xor(O5, msk);
        O6 += __shfl_xor(O6, msk); O7 += __shfl_xor(O7, msk);
    }
    if (lane < 16) {
        reinterpret_cast<float4*>(&OW[wv][0])[2 * m16]     = make_float4(O0, O1, O2, O3);
        reinterpret_cast<float4*>(&OW[wv][0])[2 * m16 + 1] = make_float4(O4, O5, O6, O7);
    }
    if (lane == 0) Zw[wv] = Zr;
    __syncthreads();

    if (t < DIM) {
        const float Zt = Zw[0] + Zw[1] + Zw[2] + Zw[3];
        out[(size_t)b * DIM + t] =
            (OW[0][t] + OW[1][t] + OW[2][t] + OW[3][t]) / Zt;
    }
}

// ---- fallback (f32 gathers, self-contained) if ws is too small ----
__global__ __launch_bounds__(256) void fused_fallback(
    const float* __restrict__ sub_feat, const float* __restrict__ mask,
    const int* __restrict__ sub_index, const float* __restrict__ ws,
    float* __restrict__ out)
{
    const int t    = threadIdx.x;
    const int lane = t & 63;
    const int wv   = t >> 6;
    const int b    = blockIdx.x;
    const int g    = lane >> 4;
    const int m16  = lane & 15;

    __shared__ float2 ibw[LEN];
    __shared__ float  g0L[DIM];
    __shared__ float  vh [2][DIM];
    __shared__ float  vL [DIM];
    __shared__ float  OW [4][DIM];
    __shared__ float  Zw [4];
    __shared__ float  qbkL;

    {
        const int   ij = sub_index[(size_t)b * LEN + t];
        const float mk = mask[(size_t)b * LEN + t];
        ibw[t] = make_float2(__int_as_float(ij), (1.f - mk) * (-10000.f * LOG2E));
    }
    if (t < 64) {
        const int r0 = sub_index[(size_t)b * LEN];
        const float2 g0p = reinterpret_cast<const float2*>(sub_feat + (size_t)r0 * DIM)[t];
        g0L[2 * t]     = g0p.x;
        g0L[2 * t + 1] = g0p.y;
        const float* w2 = ws + WS_W2;
        float qp = g0p.x * w2[2 * t] + g0p.y * w2[2 * t + 1];
        #pragma unroll
        for (int o = 32; o > 0; o >>= 1) qp += __shfl_xor(qp, o);
        if (t == 0) qbkL = (qp + ws[WS_BQBK]) * SCALE_L2;
    }
    __syncthreads();
    {
        const int i  = t & (DIM - 1);
        const int hh = t >> 7;
        const float* Mrow = ws + WS_MT + hh * 64 * DIM;
        const float* gL   = g0L + hh * 64;
        float a = 0.f;
        #pragma unroll 8
        for (int j = 0; j < 64; ++j)
            a = fmaf(gL[j], Mrow[j * DIM + i], a);
        vh[hh][i] = a;
    }
    __syncthreads();
    if (t < DIM) vL[t] = (vh[0][t] + vh[1][t] + ws[WS_C + t]) * SCALE_L2;
    __syncthreads();

    const float4 vAa = reinterpret_cast<const float4*>(vL)[2 * m16];
    const float4 vBb = reinterpret_cast<const float4*>(vL)[2 * m16 + 1];
    const float qterm = qbkL;

    float Zr = 0.f;
    float O0=0.f,O1=0.f,O2=0.f,O3=0.f,O4=0.f,O5=0.f,O6=0.f,O7=0.f;
    const int jbase = wv * 64;
    #pragma unroll 4
    for (int k = 0; k < 16; ++k) {
        const float2 ibp = ibw[jbase + 4 * k + g];
        const int   ij = __float_as_int(ibp.x);
        const float bj = ibp.y;
        const float* rp = sub_feat + (size_t)ij * DIM + 8 * m16;
        const float4 u0 = *reinterpret_cast<const float4*>(rp);
        const float4 u1 = *reinterpret_cast<const float4*>(rp + 4);
        float sd = u0.x*vAa.x + u0.y*vAa.y + u0.z*vAa.z + u0.w*vAa.w
                 + u1.x*vBb.x + u1.y*vBb.y + u1.z*vBb.z + u1.w*vBb.w;
        sd += __shfl_xor(sd, 1);
        sd += __shfl_xor(sd, 2);
        sd += __shfl_xor(sd, 4);
        sd += __shfl_xor(sd, 8);
        const float e = exp2f(sd + qterm + bj);
        Zr += e;
        O0 = fmaf(e, u0.x, O0); O1 = fmaf(e, u0.y, O1);
        O2 = fmaf(e, u0.z, O2); O3 = fmaf(e, u0.w, O3);
        O4 = fmaf(e, u1.x, O4); O5 = fmaf(e, u1.y, O5);
        O6 = fmaf(e, u1.z, O6); O7 = fmaf(e, u1.w, O7);
    }
    #pragma unroll
    for (int msk = 16; msk <= 32; msk <<= 1) {
        Zr += __shfl_xor(Zr, msk);
        O0 += __shfl_xor(O0, msk); O1 += __shfl_xor(O1, msk);
        O2 += __shfl_xor(O2, msk); O3 += __shfl_xor(O3, msk);
        O4 += __shfl_xor(O4, msk); O5 += __shfl_xor(O5, msk);
        O6 += __shfl_xor(O6, msk); O7 += __shfl_xor(O7, msk);
    }
    if (lane < 16) {
        reinterpret_cast<float4*>(&OW[wv][0])[2 * m16]     = make_float4(O0, O1, O2, O3);
        reinterpret_cast<float4*>(&OW[wv][0])[2 * m16 + 1] = make_float4(O4, O5, O6, O7);
    }
    if (lane == 0) Zw[wv] = Zr;
    __syncthreads();

    if (t < DIM) {
        const float Zt = Zw[0] + Zw[1] + Zw[2] + Zw[3];
        out[(size_t)b * DIM + t] =
            (OW[0][t] + OW[1][t] + OW[2][t] + OW[3][t]) / Zt;
    }
}

extern "C" void kernel_launch(void* const* d_in, const int* in_sizes, int n_in,
                              void* d_out, int out_size, void* d_ws, size_t ws_size,
                              hipStream_t stream) {
    const float* sub_feat  = (const float*)d_in[0];
    const float* mask      = (const float*)d_in[1];
    const float* Wq        = (const float*)d_in[2];
    const float* bq        = (const float*)d_in[3];
    const float* Wk        = (const float*)d_in[4];
    const float* bk        = (const float*)d_in[5];
    const int*   sub_index = (const int*)d_in[6];
    float* outp = (float*)d_out;
    float* ws   = (float*)d_ws;

    const int B  = in_sizes[6] / LEN;   // 2048
    const int SD = in_sizes[0];         // S*D = 524288
    const int n4 = SD / 4;

    const size_t needed = ((size_t)WS_BF + (size_t)(SD + 1) / 2) * sizeof(float);

    if (ws_size >= needed) {
        ushort* bfb = reinterpret_cast<ushort*>(ws + WS_BF);
        const int cvt_blocks = (n4 + 255) / 256;
        prep_kernel<<<dim3(DIM + 1 + cvt_blocks), dim3(256), 0, stream>>>(
            sub_feat, Wq, bq, Wk, bk, ws, bfb, n4);
        main_kernel<<<dim3(B), dim3(256), 0, stream>>>(
            sub_feat, bfb, mask, sub_index, ws, outp);
    } else {
        prep_kernel<<<dim3(DIM + 1), dim3(256), 0, stream>>>(
            sub_feat, Wq, bq, Wk, bk, ws, nullptr, 0);
        fused_fallback<<<dim3(B), dim3(256), 0, stream>>>(
            sub_feat, mask, sub_index, ws, outp);
    }
}